// Round 7
// baseline (147.534 us; speedup 1.0000x reference)
//
#include <hip/hip_runtime.h>
#include <hip/hip_bf16.h>

#define C 128
#define HW 4096
#define NPOS 65536
#define K 1024
#define MB 64             // positions per block
#define NBLK (NPOS/MB)    // 1024 = 4 blocks/CU geometry
#define RS 136            // zt row stride in ushorts (272 B)
#define TILE_B 4096       // bytes per 16-code fragment-order tile (16 codes x 128 c x 2B)

#define ZQ_OFF 0
#define LOSS_OFF 8388608
#define IDX_OFF 8388609
#define COMMIT_OFF 8454145
#define CODE_OFF 8454146

#define WS_EN_OFF 1024    // enorm1[1024] fp32 (||e||^2 + 1)
#define WS_IMG_OFF 8192   // fragment-order bf16 image, 64 tiles * 4096 B = 256 KB

typedef __bf16 bf16x8 __attribute__((ext_vector_type(8)));
typedef float f32x4 __attribute__((ext_vector_type(4)));

// Fragment-order image: tile n (codes 16n..16n+15), step ks (k=32ks..32ks+31):
//   byte offset n*4096 + ks*1024 + lane*16 holds the exact bf16x8 B-fragment
//   lane `lane` feeds to mfma_16x16x32: row nn=lane&15 (code), cols q*8..q*8+7 of this k-step.
// So the K-loop B-load is 4 lane-linear global_load_dwordx4 per tile: fully coalesced.
__global__ void vq_prep(const float* __restrict__ emb, unsigned char* __restrict__ simg,
                        float* __restrict__ enorm1, float* __restrict__ S,
                        unsigned int* __restrict__ cnt) {
    __shared__ float ps[256];
    const int n = blockIdx.x;          // tile 0..63
    const int t = threadIdx.x;
    if (n == 0 && t == 0) *S = 0.0f;
    if (n == 0 && t == 1) *cnt = 0u;
    const int ks = t >> 6, l = t & 63;
    const int nn = l & 15, q = l >> 4;
    const int r = n * 16 + nn;
    const int c0 = ks * 32 + q * 8;
    float4 v0 = *(const float4*)&emb[r * C + c0];
    float4 v1 = *(const float4*)&emb[r * C + c0 + 4];
    __hip_bfloat16 h0 = __float2bfloat16(v0.x), h1 = __float2bfloat16(v0.y),
                   h2 = __float2bfloat16(v0.z), h3 = __float2bfloat16(v0.w),
                   h4 = __float2bfloat16(v1.x), h5 = __float2bfloat16(v1.y),
                   h6 = __float2bfloat16(v1.z), h7 = __float2bfloat16(v1.w);
    ushort4 p0, p1;
    p0.x = *(unsigned short*)&h0; p0.y = *(unsigned short*)&h1;
    p0.z = *(unsigned short*)&h2; p0.w = *(unsigned short*)&h3;
    p1.x = *(unsigned short*)&h4; p1.y = *(unsigned short*)&h5;
    p1.z = *(unsigned short*)&h6; p1.w = *(unsigned short*)&h7;
    unsigned char* dst = simg + (size_t)n * TILE_B + ks * 1024 + l * 16;
    *(ushort4*)dst = p0;
    *(ushort4*)(dst + 8) = p1;
    // row norms: threads with same nn (across ks,q) cover row r's 128 cols exactly once
    ps[t] = v0.x * v0.x + v0.y * v0.y + v0.z * v0.z + v0.w * v0.w
          + v1.x * v1.x + v1.y * v1.y + v1.z * v1.z + v1.w * v1.w;
    __syncthreads();
    if (t < 16) {
        float s = 0.f;
        #pragma unroll
        for (int m = 0; m < 16; ++m) s += ps[m * 16 + t];   // index = (ks*4+q)*16 + nn
        enorm1[n * 16 + t] = s + 1.0f;
    }
}

__global__ __launch_bounds__(256, 4)
void vq_main(const float* __restrict__ z, const float* __restrict__ emb,
             const unsigned char* __restrict__ simg, const float* __restrict__ enorm1,
             float* __restrict__ out, float* __restrict__ S, unsigned int* __restrict__ cnt) {
    __shared__ unsigned short zt[MB * RS];   // 17408 B (only LDS in the hot path)
    __shared__ unsigned int wbest[4][MB];
    __shared__ unsigned short idxs[MB];
    __shared__ float lred[4];

    const int t = threadIdx.x;
    const int w = t >> 6;
    const int lane = t & 63;
    const int nn = lane & 15;
    const int q = lane >> 4;

    const int n0g = blockIdx.x * MB;
    const int b = n0g >> 12;
    const int hw0 = n0g & (HW - 1);
    const float* zg = z + (size_t)b * C * HW + hw0;

    // stage z tile -> LDS bf16 [pos][c]
    {
        int pos = t & 63;
        int c0b = (t >> 6) * 32;
        #pragma unroll
        for (int i = 0; i < 8; ++i) {
            int c0 = c0b + i * 4;
            float f0 = zg[(size_t)(c0 + 0) * HW + pos];
            float f1 = zg[(size_t)(c0 + 1) * HW + pos];
            float f2 = zg[(size_t)(c0 + 2) * HW + pos];
            float f3 = zg[(size_t)(c0 + 3) * HW + pos];
            __hip_bfloat16 h0 = __float2bfloat16(f0), h1 = __float2bfloat16(f1),
                           h2 = __float2bfloat16(f2), h3 = __float2bfloat16(f3);
            ushort4 pk;
            pk.x = *(unsigned short*)&h0; pk.y = *(unsigned short*)&h1;
            pk.z = *(unsigned short*)&h2; pk.w = *(unsigned short*)&h3;
            *(ushort4*)&zt[pos * RS + c0] = pk;
        }
    }
    __syncthreads();

    // A-frags: 4 M-tiles x 4 K-steps (64 VGPRs), reused for all 1024 codes
    bf16x8 a[4][4];
    #pragma unroll
    for (int mt = 0; mt < 4; ++mt)
        #pragma unroll
        for (int ks = 0; ks < 4; ++ks)
            a[mt][ks] = *(bf16x8*)&zt[(mt * 16 + nn) * RS + ks * 32 + q * 8];

    unsigned int best[4][4];
    #pragma unroll
    for (int mt = 0; mt < 4; ++mt)
        #pragma unroll
        for (int r = 0; r < 4; ++r) best[mt][r] = 0xFFFFFFFFu;

    // wave w owns codes [256w, 256w+256) = tiles w*16 .. w*16+15
    // K-loop: barrier-free, LDS-free; 4 coalesced dwordx4 + 16 MFMA + argmin per tile,
    // register double-buffered so next tile's loads overlap this tile's compute.
    const unsigned char* p = simg + (size_t)w * 16 * TILE_B + lane * 16;
    const float* pe = enorm1 + w * 256 + nn;

    bf16x8 bc[4], bn[4];
    #pragma unroll
    for (int ks = 0; ks < 4; ++ks) bc[ks] = *(const bf16x8*)(p + ks * 1024);
    float enc = pe[0];

    for (int it = 0; it < 16; ++it) {
        float enn = 0.f;
        if (it + 1 < 16) {
            const unsigned char* p2 = p + (size_t)(it + 1) * TILE_B;
            #pragma unroll
            for (int ks = 0; ks < 4; ++ks) bn[ks] = *(const bf16x8*)(p2 + ks * 1024);
            enn = pe[(it + 1) * 16];
        }
        const unsigned int code = (unsigned int)(w * 256 + it * 16 + nn);

        f32x4 acc[4];
        #pragma unroll
        for (int mt = 0; mt < 4; ++mt) acc[mt] = (f32x4){0.f, 0.f, 0.f, 0.f};
        #pragma unroll
        for (int ks = 0; ks < 4; ++ks)
            #pragma unroll
            for (int mt = 0; mt < 4; ++mt)
                acc[mt] = __builtin_amdgcn_mfma_f32_16x16x32_bf16(a[mt][ks], bc[ks], acc[mt], 0, 0, 0);

        // packed argmin: s = (||e||^2+1) - 2*dot in (0,2); u32-min == float-min,
        // code in low 10 bits => np tie-break (lowest index)
        #pragma unroll
        for (int mt = 0; mt < 4; ++mt)
            #pragma unroll
            for (int r = 0; r < 4; ++r) {
                float s = fmaf(acc[mt][r], -2.0f, enc);
                unsigned int u = (__float_as_uint(s) & ~1023u) | code;
                best[mt][r] = min(best[mt][r], u);
            }
        #pragma unroll
        for (int ks = 0; ks < 4; ++ks) bc[ks] = bn[ks];
        enc = enn;
    }

    // in-wave reduce over 16 code columns
    #pragma unroll
    for (int mt = 0; mt < 4; ++mt)
        #pragma unroll
        for (int r = 0; r < 4; ++r) {
            unsigned int v = best[mt][r];
            v = min(v, (unsigned int)__shfl_xor((int)v, 1));
            v = min(v, (unsigned int)__shfl_xor((int)v, 2));
            v = min(v, (unsigned int)__shfl_xor((int)v, 4));
            v = min(v, (unsigned int)__shfl_xor((int)v, 8));
            if (nn == 0) wbest[w][mt * 16 + q * 4 + r] = v;   // pos = mt*16+q*4+r
        }
    __syncthreads();

    if (t < MB) {
        unsigned int v = min(min(wbest[0][t], wbest[1][t]), min(wbest[2][t], wbest[3][t]));
        unsigned int code = v & 1023u;
        idxs[t] = (unsigned short)code;
        out[IDX_OFF + n0g + t] = (float)code;
    }
    __syncthreads();

    // epilogue: exact fp32 gather from emb (L2-hot), z_q store, loss
    {
        int pos = t & 63;
        int c0b = (t >> 6) * 32;
        int myidx = idxs[pos];
        const float* erow = emb + (size_t)myidx * C;
        float* og = out + ZQ_OFF + (size_t)b * C * HW + hw0;
        float ls = 0.f;
        #pragma unroll
        for (int i = 0; i < 8; ++i) {
            int c0 = c0b + i * 4;
            float4 ev = *(const float4*)&erow[c0];
            ushort4 zz = *(ushort4*)&zt[pos * RS + c0];
            float z0 = __uint_as_float((unsigned int)zz.x << 16);
            float z1 = __uint_as_float((unsigned int)zz.y << 16);
            float z2 = __uint_as_float((unsigned int)zz.z << 16);
            float z3 = __uint_as_float((unsigned int)zz.w << 16);
            float d0 = z0 - ev.x, d1 = z1 - ev.y, d2 = z2 - ev.z, d3 = z3 - ev.w;
            ls += d0 * d0 + d1 * d1 + d2 * d2 + d3 * d3;
            og[(size_t)(c0 + 0) * HW + pos] = ev.x;
            og[(size_t)(c0 + 1) * HW + pos] = ev.y;
            og[(size_t)(c0 + 2) * HW + pos] = ev.z;
            og[(size_t)(c0 + 3) * HW + pos] = ev.w;
        }
        #pragma unroll
        for (int off = 32; off; off >>= 1) ls += __shfl_down(ls, off);
        if (lane == 0) lred[w] = ls;
    }
    __syncthreads();

    if (t == 0) {
        atomicAdd(S, lred[0] + lred[1] + lred[2] + lred[3]);
        __threadfence();
        unsigned int old = atomicAdd(cnt, 1u);
        if (old == NBLK - 1) {
            float s = atomicAdd(S, 0.0f);
            out[LOSS_OFF] = 1.25f * s;
            out[COMMIT_OFF] = 0.25f * s;
            out[CODE_OFF] = s;
        }
    }
}

extern "C" void kernel_launch(void* const* d_in, const int* in_sizes, int n_in,
                              void* d_out, int out_size, void* d_ws, size_t ws_size,
                              hipStream_t stream) {
    const float* z = (const float*)d_in[0];
    const float* emb = (const float*)d_in[1];
    float* out = (float*)d_out;
    float* S = (float*)d_ws;
    unsigned int* cnt = (unsigned int*)d_ws + 1;
    float* enorm1 = (float*)((unsigned char*)d_ws + WS_EN_OFF);
    unsigned char* simg = (unsigned char*)d_ws + WS_IMG_OFF;

    vq_prep<<<K / 16, 256, 0, stream>>>(emb, simg, enorm1, S, cnt);
    vq_main<<<NBLK, 256, 0, stream>>>(z, emb, simg, enorm1, out, S, cnt);
}

// Round 8
// 145.438 us; speedup vs baseline: 1.0144x; 1.0144x over previous
//
#include <hip/hip_runtime.h>
#include <hip/hip_bf16.h>

#define C 128
#define HW 4096
#define NPOS 65536
#define K 1024
#define MB 64             // positions per block
#define NBLK (NPOS/MB)    // 1024 = 4 blocks/CU geometry
#define RS 136            // zt row stride in ushorts (272 B)
#define TILE_B 4096       // bytes per 16-code fragment-order tile

#define ZQ_OFF 0
#define LOSS_OFF 8388608
#define IDX_OFF 8388609
#define COMMIT_OFF 8454145
#define CODE_OFF 8454146

#define WS_EN_OFF 1024    // enorm1[1024] fp32 (||e||^2 + 1)
#define WS_IMG_OFF 8192   // fragment-order bf16 image, 64 tiles * 4096 B

typedef __bf16 bf16x8 __attribute__((ext_vector_type(8)));
typedef float f32x4 __attribute__((ext_vector_type(4)));

// Fragment-order image: tile n (codes 16n..15), step ks: byte offset
// n*4096 + ks*1024 + lane*16 = the bf16x8 B-fragment for lane (nn=code, q=col-block).
__global__ void vq_prep(const float* __restrict__ emb, unsigned char* __restrict__ simg,
                        float* __restrict__ enorm1, float* __restrict__ S,
                        unsigned int* __restrict__ cnt) {
    __shared__ float ps[256];
    const int n = blockIdx.x;
    const int t = threadIdx.x;
    if (n == 0 && t == 0) *S = 0.0f;
    if (n == 0 && t == 1) *cnt = 0u;
    const int ks = t >> 6, l = t & 63;
    const int nn = l & 15, q = l >> 4;
    const int r = n * 16 + nn;
    const int c0 = ks * 32 + q * 8;
    float4 v0 = *(const float4*)&emb[r * C + c0];
    float4 v1 = *(const float4*)&emb[r * C + c0 + 4];
    __hip_bfloat16 h0 = __float2bfloat16(v0.x), h1 = __float2bfloat16(v0.y),
                   h2 = __float2bfloat16(v0.z), h3 = __float2bfloat16(v0.w),
                   h4 = __float2bfloat16(v1.x), h5 = __float2bfloat16(v1.y),
                   h6 = __float2bfloat16(v1.z), h7 = __float2bfloat16(v1.w);
    ushort4 p0, p1;
    p0.x = *(unsigned short*)&h0; p0.y = *(unsigned short*)&h1;
    p0.z = *(unsigned short*)&h2; p0.w = *(unsigned short*)&h3;
    p1.x = *(unsigned short*)&h4; p1.y = *(unsigned short*)&h5;
    p1.z = *(unsigned short*)&h6; p1.w = *(unsigned short*)&h7;
    unsigned char* dst = simg + (size_t)n * TILE_B + ks * 1024 + l * 16;
    *(ushort4*)dst = p0;
    *(ushort4*)(dst + 8) = p1;
    ps[t] = v0.x * v0.x + v0.y * v0.y + v0.z * v0.z + v0.w * v0.w
          + v1.x * v1.x + v1.y * v1.y + v1.z * v1.z + v1.w * v1.w;
    __syncthreads();
    if (t < 16) {
        float s = 0.f;
        #pragma unroll
        for (int m = 0; m < 16; ++m) s += ps[m * 16 + t];
        enorm1[n * 16 + t] = s + 1.0f;
    }
}

// Pin exactly 4 waves/EU: 128-VGPR budget so A-frags genuinely live in registers.
// (Without this the backend sees 19 KB LDS, targets 8 waves/EU, allocates 64 VGPRs
//  and spills/rematerializes the whole K-loop — R4..R7's hidden failure mode.)
__global__ void __launch_bounds__(256)
__attribute__((amdgpu_waves_per_eu(4, 4)))
vq_main(const float* __restrict__ z, const float* __restrict__ emb,
        const unsigned char* __restrict__ simg, const float* __restrict__ enorm1,
        float* __restrict__ out, float* __restrict__ S, unsigned int* __restrict__ cnt) {
    __shared__ unsigned short zt[MB * RS];   // 17408 B
    __shared__ unsigned int wbest[4][MB];
    __shared__ unsigned short idxs[MB];
    __shared__ float lred[4];

    const int t = threadIdx.x;
    const int w = t >> 6;
    const int lane = t & 63;
    const int nn = lane & 15;
    const int q = lane >> 4;

    const int n0g = blockIdx.x * MB;
    const int b = n0g >> 12;
    const int hw0 = n0g & (HW - 1);
    const float* zg = z + (size_t)b * C * HW + hw0;

    // stage z tile -> LDS bf16 [pos][c]
    {
        int pos = t & 63;
        int c0b = (t >> 6) * 32;
        #pragma unroll
        for (int i = 0; i < 8; ++i) {
            int c0 = c0b + i * 4;
            float f0 = zg[(size_t)(c0 + 0) * HW + pos];
            float f1 = zg[(size_t)(c0 + 1) * HW + pos];
            float f2 = zg[(size_t)(c0 + 2) * HW + pos];
            float f3 = zg[(size_t)(c0 + 3) * HW + pos];
            __hip_bfloat16 h0 = __float2bfloat16(f0), h1 = __float2bfloat16(f1),
                           h2 = __float2bfloat16(f2), h3 = __float2bfloat16(f3);
            ushort4 pk;
            pk.x = *(unsigned short*)&h0; pk.y = *(unsigned short*)&h1;
            pk.z = *(unsigned short*)&h2; pk.w = *(unsigned short*)&h3;
            *(ushort4*)&zt[pos * RS + c0] = pk;
        }
    }
    __syncthreads();

    // A-frags: 4 M-tiles x 4 K-steps = 64 VGPRs, loaded ONCE, reused for all 1024 codes
    bf16x8 a[4][4];
    #pragma unroll
    for (int mt = 0; mt < 4; ++mt)
        #pragma unroll
        for (int ks = 0; ks < 4; ++ks)
            a[mt][ks] = *(bf16x8*)&zt[(mt * 16 + nn) * RS + ks * 32 + q * 8];

    unsigned int best[4][4];
    #pragma unroll
    for (int mt = 0; mt < 4; ++mt)
        #pragma unroll
        for (int r = 0; r < 4; ++r) best[mt][r] = 0xFFFFFFFFu;

    // wave w owns codes [256w, 256w+256) = tiles w*16..w*16+15.
    // Barrier-free, LDS-free K-loop: 4 coalesced dwordx4 + 16 MFMA + argmin per tile.
    // No register double-buffer (fits 128 VGPRs); 4 waves/SIMD TLP hides L2 latency.
    const unsigned char* p = simg + (size_t)w * 16 * TILE_B + lane * 16;
    const float* pe = enorm1 + w * 256 + nn;

    for (int it = 0; it < 16; ++it) {
        const unsigned char* pt = p + (size_t)it * TILE_B;
        bf16x8 bc[4];
        #pragma unroll
        for (int ks = 0; ks < 4; ++ks) bc[ks] = *(const bf16x8*)(pt + ks * 1024);
        const float enc = pe[it * 16];
        const unsigned int code = (unsigned int)(w * 256 + it * 16 + nn);

        f32x4 acc[4];
        #pragma unroll
        for (int mt = 0; mt < 4; ++mt) acc[mt] = (f32x4){0.f, 0.f, 0.f, 0.f};
        #pragma unroll
        for (int ks = 0; ks < 4; ++ks)
            #pragma unroll
            for (int mt = 0; mt < 4; ++mt)
                acc[mt] = __builtin_amdgcn_mfma_f32_16x16x32_bf16(a[mt][ks], bc[ks], acc[mt], 0, 0, 0);

        // packed argmin: s = (||e||^2+1) - 2*dot in (0,2); u32-min == float-min,
        // code in low 10 bits => np tie-break (lowest index)
        #pragma unroll
        for (int mt = 0; mt < 4; ++mt)
            #pragma unroll
            for (int r = 0; r < 4; ++r) {
                float s = fmaf(acc[mt][r], -2.0f, enc);
                unsigned int u = (__float_as_uint(s) & ~1023u) | code;
                best[mt][r] = min(best[mt][r], u);
            }
    }

    // in-wave reduce over 16 code columns
    #pragma unroll
    for (int mt = 0; mt < 4; ++mt)
        #pragma unroll
        for (int r = 0; r < 4; ++r) {
            unsigned int v = best[mt][r];
            v = min(v, (unsigned int)__shfl_xor((int)v, 1));
            v = min(v, (unsigned int)__shfl_xor((int)v, 2));
            v = min(v, (unsigned int)__shfl_xor((int)v, 4));
            v = min(v, (unsigned int)__shfl_xor((int)v, 8));
            if (nn == 0) wbest[w][mt * 16 + q * 4 + r] = v;   // pos = mt*16+q*4+r
        }
    __syncthreads();

    if (t < MB) {
        unsigned int v = min(min(wbest[0][t], wbest[1][t]), min(wbest[2][t], wbest[3][t]));
        unsigned int code = v & 1023u;
        idxs[t] = (unsigned short)code;
        out[IDX_OFF + n0g + t] = (float)code;
    }
    __syncthreads();

    // epilogue: exact fp32 gather from emb (L2-hot), z_q store, loss
    {
        int pos = t & 63;
        int c0b = (t >> 6) * 32;
        int myidx = idxs[pos];
        const float* erow = emb + (size_t)myidx * C;
        float* og = out + ZQ_OFF + (size_t)b * C * HW + hw0;
        float ls = 0.f;
        #pragma unroll
        for (int i = 0; i < 8; ++i) {
            int c0 = c0b + i * 4;
            float4 ev = *(const float4*)&erow[c0];
            ushort4 zz = *(ushort4*)&zt[pos * RS + c0];
            float z0 = __uint_as_float((unsigned int)zz.x << 16);
            float z1 = __uint_as_float((unsigned int)zz.y << 16);
            float z2 = __uint_as_float((unsigned int)zz.z << 16);
            float z3 = __uint_as_float((unsigned int)zz.w << 16);
            float d0 = z0 - ev.x, d1 = z1 - ev.y, d2 = z2 - ev.z, d3 = z3 - ev.w;
            ls += d0 * d0 + d1 * d1 + d2 * d2 + d3 * d3;
            og[(size_t)(c0 + 0) * HW + pos] = ev.x;
            og[(size_t)(c0 + 1) * HW + pos] = ev.y;
            og[(size_t)(c0 + 2) * HW + pos] = ev.z;
            og[(size_t)(c0 + 3) * HW + pos] = ev.w;
        }
        #pragma unroll
        for (int off = 32; off; off >>= 1) ls += __shfl_down(ls, off);
        if (lane == 0) lred[w] = ls;
    }
    __syncthreads();

    if (t == 0) {
        atomicAdd(S, lred[0] + lred[1] + lred[2] + lred[3]);
        __threadfence();
        unsigned int old = atomicAdd(cnt, 1u);
        if (old == NBLK - 1) {
            float s = atomicAdd(S, 0.0f);
            out[LOSS_OFF] = 1.25f * s;
            out[COMMIT_OFF] = 0.25f * s;
            out[CODE_OFF] = s;
        }
    }
}

extern "C" void kernel_launch(void* const* d_in, const int* in_sizes, int n_in,
                              void* d_out, int out_size, void* d_ws, size_t ws_size,
                              hipStream_t stream) {
    const float* z = (const float*)d_in[0];
    const float* emb = (const float*)d_in[1];
    float* out = (float*)d_out;
    float* S = (float*)d_ws;
    unsigned int* cnt = (unsigned int*)d_ws + 1;
    float* enorm1 = (float*)((unsigned char*)d_ws + WS_EN_OFF);
    unsigned char* simg = (unsigned char*)d_ws + WS_IMG_OFF;

    vq_prep<<<K / 16, 256, 0, stream>>>(emb, simg, enorm1, S, cnt);
    vq_main<<<NBLK, 256, 0, stream>>>(z, emb, simg, enorm1, out, S, cnt);
}